// Round 2
// baseline (1523.914 us; speedup 1.0000x reference)
//
#include <hip/hip_runtime.h>
#include <hip/hip_bf16.h>
#include <stdint.h>

using bf16 = __hip_bfloat16;
typedef __attribute__((ext_vector_type(8))) short s16x8;
typedef __attribute__((ext_vector_type(8))) unsigned short u16x8;
typedef __attribute__((ext_vector_type(4))) unsigned short u16x4;
typedef __attribute__((ext_vector_type(4))) float f32x4;

__device__ __forceinline__ float bu2f(unsigned short u) {
    union { unsigned int i; float f; } v; v.i = ((unsigned int)u) << 16; return v.f;
}
__device__ __forceinline__ float b2f(bf16 v) { return __bfloat162float(v); }
__device__ __forceinline__ bf16 f2b(float f) { return __float2bfloat16(f); }
__device__ __forceinline__ unsigned short f2bu(float f) {
    bf16 t = __float2bfloat16(f); return *(unsigned short*)&t;
}
__device__ __forceinline__ void st(bf16* p, float v) { *p = f2b(v); }
__device__ __forceinline__ void st(float* p, float v) { *p = v; }

#define AS1(p) ((__attribute__((address_space(1))) void*)(p))
#define AS3(p) ((__attribute__((address_space(3))) void*)(p))

// ---------------------------------------------------------------- weight cast f32 -> bf16
// 10 segments packed into one bf16 arena; i = vec8 index
__global__ __launch_bounds__(256) void cast_weights_k(
    const float* __restrict__ s0, const float* __restrict__ s1,
    const float* __restrict__ s2, const float* __restrict__ s3,
    const float* __restrict__ s4, const float* __restrict__ s5,
    const float* __restrict__ s6, const float* __restrict__ s7,
    const float* __restrict__ s8, const float* __restrict__ s9,
    bf16* __restrict__ dst)
{
    int i = blockIdx.x * 256 + threadIdx.x;
    const float* src; int loc;
    if      (i < 131072) { src = s0; loc = i; }
    else if (i < 262144) { src = s1; loc = i - 131072; }
    else if (i < 270336) { src = s2; loc = i - 262144; }
    else if (i < 278528) { src = s3; loc = i - 270336; }
    else if (i < 282624) { src = s4; loc = i - 278528; }
    else if (i < 286720) { src = s5; loc = i - 282624; }
    else if (i < 352256) { src = s6; loc = i - 286720; }
    else if (i < 417792) { src = s7; loc = i - 352256; }
    else if (i < 548864) { src = s8; loc = i - 417792; }
    else                 { src = s9; loc = i - 548864; }
    f32x4 a = *(const f32x4*)(src + (size_t)loc * 8);
    f32x4 b = *(const f32x4*)(src + (size_t)loc * 8 + 4);
    u16x8 o;
#pragma unroll
    for (int j = 0; j < 4; j++) { o[j] = f2bu(a[j]); o[4 + j] = f2bu(b[j]); }
    *(u16x8*)(dst + (size_t)i * 8) = o;
}

// ---------------------------------------------------------------- layernorm (f32 in, bf16 out)
// one wave per 512-el row; block = 4 rows
__global__ __launch_bounds__(256) void layernorm_k(
    const float* __restrict__ x, const float* __restrict__ g, const float* __restrict__ bb,
    bf16* __restrict__ out, int rows_per_b, int out_bstride, int out_roff)
{
    int r = blockIdx.x * 4 + (threadIdx.x >> 6);
    int lane = threadIdx.x & 63;
    const float* xr = x + (size_t)r * 512 + lane * 8;
    f32x4 v0 = *(const f32x4*)(xr);
    f32x4 v1 = *(const f32x4*)(xr + 4);
    float f[8]; float s = 0.f, s2 = 0.f;
#pragma unroll
    for (int j = 0; j < 4; j++) { f[j] = v0[j]; f[4 + j] = v1[j]; }
#pragma unroll
    for (int j = 0; j < 8; j++) { s += f[j]; s2 += f[j] * f[j]; }
#pragma unroll
    for (int o = 1; o < 64; o <<= 1) { s += __shfl_xor(s, o); s2 += __shfl_xor(s2, o); }
    float mu = s * (1.f / 512.f);
    float var = s2 * (1.f / 512.f) - mu * mu;
    float rs = rsqrtf(var + 1e-5f);
    f32x4 g0 = *(const f32x4*)(g + lane * 8);
    f32x4 g1 = *(const f32x4*)(g + lane * 8 + 4);
    f32x4 b0 = *(const f32x4*)(bb + lane * 8);
    f32x4 b1 = *(const f32x4*)(bb + lane * 8 + 4);
    int b = r / rows_per_b, rr = r % rows_per_b;
    bf16* orow = out + ((size_t)b * out_bstride + out_roff + rr) * 512 + lane * 8;
    u16x8 ov;
#pragma unroll
    for (int j = 0; j < 4; j++) {
        ov[j]     = f2bu((f[j]     - mu) * rs * g0[j] + b0[j]);
        ov[4 + j] = f2bu((f[4 + j] - mu) * rs * g1[j] + b1[j]);
    }
    *(u16x8*)orow = ov;
}

// ---------------------------------------------------------------- GEMM  C = epi(A * W^T)
// A: (M,K) bf16 row-major lda; W: (N,K) bf16 row-major; C: (M,N) OT ldc
// tile 128x128, BK=32, 4 waves (2x2), each wave 64x64 via 4x4 mfma 16x16x32
enum { EPI_NONE = 0, EPI_SOFTPLUS = 1, EPI_RES = 2, EPI_RELU = 3, EPI_BIAS_RES = 4 };

template<int EPI, typename OT>
__global__ __launch_bounds__(256, 2) void gemm_bt(
    const bf16* __restrict__ A, int lda,
    const bf16* __restrict__ Wt,
    const float* __restrict__ bias,
    const float* __restrict__ res, int ldres,
    OT* __restrict__ C, int ldc,
    int M, int N, int K)
{
    __shared__ __align__(16) bf16 lA[128 * 32];
    __shared__ __align__(16) bf16 lB[128 * 32];
    const int t = threadIdx.x;
    const int bm = blockIdx.x * 128;
    const int bn = blockIdx.y * 128;
    const int w = t >> 6, l = t & 63;
    const int wm = (w >> 1) * 64, wn = (w & 1) * 64;
    const int lr = l & 15, lk = (l >> 4) * 8;
    f32x4 acc[4][4] = {};

    const int c0 = t, c1 = t + 256;
    const int r0 = c0 >> 2, k0o = (c0 & 3) * 8;
    const int r1 = c1 >> 2, k1o = (c1 & 3) * 8;
    int rb0 = bn + r0; if (rb0 >= N) rb0 = N - 1;
    int rb1 = bn + r1; if (rb1 >= N) rb1 = N - 1;

    for (int kk = 0; kk < K; kk += 32) {
        __builtin_amdgcn_global_load_lds(AS1(A + (size_t)(bm + r0) * lda + kk + k0o), AS3(lA + c0 * 8), 16, 0, 0);
        __builtin_amdgcn_global_load_lds(AS1(A + (size_t)(bm + r1) * lda + kk + k1o), AS3(lA + c1 * 8), 16, 0, 0);
        __builtin_amdgcn_global_load_lds(AS1(Wt + (size_t)rb0 * K + kk + k0o), AS3(lB + c0 * 8), 16, 0, 0);
        __builtin_amdgcn_global_load_lds(AS1(Wt + (size_t)rb1 * K + kk + k1o), AS3(lB + c1 * 8), 16, 0, 0);
        asm volatile("s_waitcnt vmcnt(0)" ::: "memory");
        __syncthreads();
        s16x8 af[4], bfr[4];
#pragma unroll
        for (int m = 0; m < 4; m++) af[m] = *(const s16x8*)(lA + (wm + m * 16 + lr) * 32 + lk);
#pragma unroll
        for (int n = 0; n < 4; n++) bfr[n] = *(const s16x8*)(lB + (wn + n * 16 + lr) * 32 + lk);
#pragma unroll
        for (int m = 0; m < 4; m++)
#pragma unroll
            for (int n = 0; n < 4; n++)
                acc[m][n] = __builtin_amdgcn_mfma_f32_16x16x32_bf16(af[m], bfr[n], acc[m][n], 0, 0, 0);
        __syncthreads();
    }

#pragma unroll
    for (int n = 0; n < 4; n++) {
        int col = bn + wn + n * 16 + lr;
        if (col >= N) continue;
        float bv = 0.f;
        if (EPI == EPI_SOFTPLUS || EPI == EPI_RELU || EPI == EPI_BIAS_RES) bv = bias[col];
#pragma unroll
        for (int m = 0; m < 4; m++) {
#pragma unroll
            for (int i = 0; i < 4; i++) {
                int row = bm + wm + m * 16 + (l >> 4) * 4 + i;
                float v = acc[m][n][i] + bv;
                if (EPI == EPI_SOFTPLUS) v = (v > 20.f) ? v : log1pf(__expf(v));
                if (EPI == EPI_RELU) v = fmaxf(v, 0.f);
                if (EPI == EPI_RES || EPI == EPI_BIAS_RES) v += res[(size_t)row * ldres + col];
                st(&C[(size_t)row * ldc + col], v);
            }
        }
    }
}

// ---------------------------------------------------------------- causal depthwise conv (D_CONV=4) + silu
// grid.x = B*Ltot (one (b,t) per block), 128 threads x 8 channels
__global__ __launch_bounds__(128) void conv_silu_k(
    const bf16* __restrict__ xz, const float* __restrict__ cw, const float* __restrict__ cb,
    bf16* __restrict__ xi, int Ltot)
{
    int row = blockIdx.x;
    int tt = row % Ltot;
    int d0 = threadIdx.x * 8;
    float w[4][8];
#pragma unroll
    for (int j = 0; j < 8; j++) {
        f32x4 wv = *(const f32x4*)(cw + (size_t)(d0 + j) * 4);
#pragma unroll
        for (int tap = 0; tap < 4; tap++) w[tap][j] = wv[tap];
    }
    f32x4 cb0 = *(const f32x4*)(cb + d0);
    f32x4 cb1 = *(const f32x4*)(cb + d0 + 4);
    float acc[8];
#pragma unroll
    for (int j = 0; j < 4; j++) { acc[j] = cb0[j]; acc[4 + j] = cb1[j]; }
#pragma unroll
    for (int tap = 0; tap < 4; tap++) {
        int ts = tt - 3 + tap;
        if (ts < 0) continue;
        const u16x8 v = *(const u16x8*)(xz + (size_t)(row - 3 + tap) * 2048 + d0);
#pragma unroll
        for (int j = 0; j < 8; j++) acc[j] = fmaf(w[tap][j], bu2f(v[j]), acc[j]);
    }
    u16x8 ov;
#pragma unroll
    for (int j = 0; j < 8; j++) {
        float a = acc[j];
        ov[j] = f2bu(a / (1.f + __expf(-a)));
    }
    *(u16x8*)(xi + (size_t)row * 1024 + d0) = ov;
}

// ---------------------------------------------------------------- selective scan
// thread = (b, d, n): lane = dloc*16 + n ; 16 d per block (4 waves x 4 dloc)
// 8-deep register prefetch (statically unrolled) to hide L2/L3 latency at 1 wave/SIMD
__global__ __launch_bounds__(256) void scan_k(
    const bf16* __restrict__ delta, const bf16* __restrict__ dbc,
    const bf16* __restrict__ xi, const bf16* __restrict__ xz,
    const float* __restrict__ A_log, const float* __restrict__ Dp,
    bf16* __restrict__ y, int Ltot, int Lout)
{
    const int t = threadIdx.x;
    const int lane = t & 63, wv = t >> 6;
    const int n = lane & 15, dloc = lane >> 4;
    const int b = blockIdx.x >> 6, dblk = blockIdx.x & 63;
    const int d = dblk * 16 + wv * 4 + dloc;
    const float Af = -__expf(A_log[d * 16 + n]) * 1.442695040888963f; // * log2(e)
    const float Dv = Dp[d];
    const int tstart = Ltot - Lout;
    const size_t r = (size_t)b * Ltot;
    float h = 0.f;
    float dl[8], xv[8], Bv[8], Cv[8], zv[8];
#pragma unroll
    for (int j = 0; j < 8; j++) {
        size_t rn = r + j;
        dl[j] = b2f(delta[rn * 1024 + d]);
        xv[j] = b2f(xi[rn * 1024 + d]);
        Bv[j] = b2f(dbc[rn * 64 + 32 + n]);
        Cv[j] = b2f(dbc[rn * 64 + 48 + n]);
        zv[j] = b2f(xz[rn * 2048 + 1024 + d]);
    }
    for (int t0 = 0; t0 < Ltot; t0 += 8) {
        float dl2[8], xv2[8], Bv2[8], Cv2[8], zv2[8];
        const int tn = t0 + 8;
        if (tn < Ltot) {
#pragma unroll
            for (int j = 0; j < 8; j++) {
                size_t rn = r + tn + j;
                dl2[j] = b2f(delta[rn * 1024 + d]);
                xv2[j] = b2f(xi[rn * 1024 + d]);
                Bv2[j] = b2f(dbc[rn * 64 + 32 + n]);
                Cv2[j] = b2f(dbc[rn * 64 + 48 + n]);
                zv2[j] = b2f(xz[rn * 2048 + 1024 + d]);
            }
        } else {
#pragma unroll
            for (int j = 0; j < 8; j++) { dl2[j] = 0.f; xv2[j] = 0.f; Bv2[j] = 0.f; Cv2[j] = 0.f; zv2[j] = 0.f; }
        }
#pragma unroll
        for (int j = 0; j < 8; j++) {
            int tt = t0 + j;
            float dA = exp2f(dl[j] * Af);
            h = fmaf(dA, h, dl[j] * Bv[j] * xv[j]);
            float s = h * Cv[j];
            s += __shfl_xor(s, 1); s += __shfl_xor(s, 2);
            s += __shfl_xor(s, 4); s += __shfl_xor(s, 8);
            if (tt >= tstart && n == 0) {
                float z = zv[j];
                float yv = (s + xv[j] * Dv) * (z / (1.f + __expf(-z)));
                y[((size_t)b * Lout + (tt - tstart)) * 1024 + d] = f2b(yv);
            }
        }
#pragma unroll
        for (int j = 0; j < 8; j++) { dl[j] = dl2[j]; xv[j] = xv2[j]; Bv[j] = Bv2[j]; Cv[j] = Cv2[j]; zv[j] = zv2[j]; }
    }
}

// ---------------------------------------------------------------- enc_out (f32) -> xcat rows [0,1024) (bf16)
__global__ __launch_bounds__(256) void copy_enc_k(const float* __restrict__ enc, bf16* __restrict__ xcat)
{
    size_t i = (size_t)blockIdx.x * 256 + threadIdx.x;  // vec8 index, 65536 per batch
    size_t b = i >> 16;
    size_t off = (i & 65535) * 8;
    const float* src = enc + b * (1024 * 512) + off;
    f32x4 a = *(const f32x4*)(src);
    f32x4 c = *(const f32x4*)(src + 4);
    u16x8 o;
#pragma unroll
    for (int j = 0; j < 4; j++) { o[j] = f2bu(a[j]); o[4 + j] = f2bu(c[j]); }
    *(u16x8*)(xcat + b * (2048 * 512) + off) = o;
}

// ---------------------------------------------------------------- launch
extern "C" void kernel_launch(void* const* d_in, const int* in_sizes, int n_in,
                              void* d_out, int out_size, void* d_ws, size_t ws_size,
                              hipStream_t stream)
{
    const float* x      = (const float*)d_in[0];
    const float* enc    = (const float*)d_in[1];
    const float* ln1g   = (const float*)d_in[2];
    const float* ln1b   = (const float*)d_in[3];
    const float* ln2g   = (const float*)d_in[4];
    const float* ln2b   = (const float*)d_in[5];
    const float* ln3g   = (const float*)d_in[6];
    const float* ln3b   = (const float*)d_in[7];
    const float* ffw1   = (const float*)d_in[8];
    const float* ffb1   = (const float*)d_in[9];
    const float* ffw2   = (const float*)d_in[10];
    const float* ffb2   = (const float*)d_in[11];
    const float* u_in_w   = (const float*)d_in[12];
    const float* u_conv_w = (const float*)d_in[13];
    const float* u_conv_b = (const float*)d_in[14];
    const float* u_xproj  = (const float*)d_in[15];
    const float* u_dt_w   = (const float*)d_in[16];
    const float* u_dt_b   = (const float*)d_in[17];
    const float* u_A_log  = (const float*)d_in[18];
    const float* u_D      = (const float*)d_in[19];
    const float* u_out_w  = (const float*)d_in[20];
    const float* c_in_w   = (const float*)d_in[21];
    const float* c_conv_w = (const float*)d_in[22];
    const float* c_conv_b = (const float*)d_in[23];
    const float* c_xproj  = (const float*)d_in[24];
    const float* c_dt_w   = (const float*)d_in[25];
    const float* c_dt_b   = (const float*)d_in[26];
    const float* c_A_log  = (const float*)d_in[27];
    const float* c_D      = (const float*)d_in[28];
    const float* c_out_w  = (const float*)d_in[29];

    const size_t MB = 1ull << 20;
    char* W = (char*)d_ws;
    float* h   = (float*)(W + 0 * MB);     // (4,1024,512) f32  8MB  persistent
    float* h2  = (float*)(W + 8 * MB);     // (4,1024,512) f32  8MB  persistent
    bf16*  wts = (bf16*)(W + 16 * MB);     // packed bf16 weights 10.4MB persistent
    // bf16-weight arena offsets (elements)
    const size_t W_u_in  = 0;
    const size_t W_c_in  = 1048576;
    const size_t W_u_xp  = 2097152;
    const size_t W_c_xp  = 2162688;
    const size_t W_u_dt  = 2228224;
    const size_t W_c_dt  = 2260992;
    const size_t W_u_out = 2293760;
    const size_t W_c_out = 2818048;
    const size_t W_ff1   = 3342336;
    const size_t W_ff2   = 4390912;
    // self phase arena
    bf16* s_ln1 = (bf16*)(W + 28 * MB);    // 4MB
    bf16* s_xz  = (bf16*)(W + 32 * MB);    // 16MB (4,1024,2048)
    bf16* s_xi  = (bf16*)(W + 48 * MB);    // 8MB
    bf16* s_dbc = (bf16*)(W + 56 * MB);    // 0.5MB
    bf16* s_dl  = (bf16*)(W + 57 * MB);    // 8MB
    bf16* s_y   = (bf16*)(W + 65 * MB);    // 8MB  -> end 73MB
    // cross phase arena
    bf16* c_xcat = (bf16*)(W + 28 * MB);   // 8MB  (4,2048,512)
    bf16* c_xz   = (bf16*)(W + 36 * MB);   // 32MB (4,2048,2048)
    bf16* c_xi   = (bf16*)(W + 68 * MB);   // 16MB (4,2048,1024)
    bf16* c_dbc  = (bf16*)(W + 84 * MB);   // 1MB
    bf16* c_dl   = (bf16*)(W + 85 * MB);   // 16MB -> end 101MB
    bf16* c_y    = (bf16*)(W + 28 * MB);   // 8MB  reuses c_xcat (dead after in-proj GEMM)
    // ff phase arena
    bf16* f_ln3 = (bf16*)(W + 28 * MB);    // 4MB
    bf16* f_ff1 = (bf16*)(W + 32 * MB);    // 16MB (4,1024,2048)

    // weight cast (every launch; deterministic)
    cast_weights_k<<<2656, 256, 0, stream>>>(u_in_w, c_in_w, u_xproj, c_xproj, u_dt_w,
                                             c_dt_w, u_out_w, c_out_w, ffw1, ffw2, wts);

    // ---------------- self mamba ----------------
    layernorm_k<<<1024, 256, 0, stream>>>(x, ln1g, ln1b, s_ln1, 1024, 1024, 0);
    gemm_bt<EPI_NONE, bf16><<<dim3(32, 16), 256, 0, stream>>>(s_ln1, 512, wts + W_u_in, nullptr, nullptr, 0, s_xz, 2048, 4096, 2048, 512);
    conv_silu_k<<<4096, 128, 0, stream>>>(s_xz, u_conv_w, u_conv_b, s_xi, 1024);
    gemm_bt<EPI_NONE, bf16><<<dim3(32, 1), 256, 0, stream>>>(s_xi, 1024, wts + W_u_xp, nullptr, nullptr, 0, s_dbc, 64, 4096, 64, 1024);
    gemm_bt<EPI_SOFTPLUS, bf16><<<dim3(32, 8), 256, 0, stream>>>(s_dbc, 64, wts + W_u_dt, u_dt_b, nullptr, 0, s_dl, 1024, 4096, 1024, 32);
    scan_k<<<256, 256, 0, stream>>>(s_dl, s_dbc, s_xi, s_xz, u_A_log, u_D, s_y, 1024, 1024);
    gemm_bt<EPI_RES, float><<<dim3(32, 4), 256, 0, stream>>>(s_y, 1024, wts + W_u_out, nullptr, x, 512, h, 512, 4096, 512, 1024);

    // ---------------- cross mamba ----------------
    copy_enc_k<<<1024, 256, 0, stream>>>(enc, c_xcat);
    layernorm_k<<<1024, 256, 0, stream>>>(h, ln2g, ln2b, c_xcat, 1024, 2048, 1024);
    gemm_bt<EPI_NONE, bf16><<<dim3(64, 16), 256, 0, stream>>>(c_xcat, 512, wts + W_c_in, nullptr, nullptr, 0, c_xz, 2048, 8192, 2048, 512);
    conv_silu_k<<<8192, 128, 0, stream>>>(c_xz, c_conv_w, c_conv_b, c_xi, 2048);
    gemm_bt<EPI_NONE, bf16><<<dim3(64, 1), 256, 0, stream>>>(c_xi, 1024, wts + W_c_xp, nullptr, nullptr, 0, c_dbc, 64, 8192, 64, 1024);
    gemm_bt<EPI_SOFTPLUS, bf16><<<dim3(64, 8), 256, 0, stream>>>(c_dbc, 64, wts + W_c_dt, c_dt_b, nullptr, 0, c_dl, 1024, 8192, 1024, 32);
    scan_k<<<256, 256, 0, stream>>>(c_dl, c_dbc, c_xi, c_xz, c_A_log, c_D, c_y, 2048, 1024);
    gemm_bt<EPI_RES, float><<<dim3(32, 4), 256, 0, stream>>>(c_y, 1024, wts + W_c_out, nullptr, h, 512, h2, 512, 4096, 512, 1024);

    // ---------------- feed-forward ----------------
    layernorm_k<<<1024, 256, 0, stream>>>(h2, ln3g, ln3b, f_ln3, 1024, 1024, 0);
    gemm_bt<EPI_RELU, bf16><<<dim3(32, 16), 256, 0, stream>>>(f_ln3, 512, wts + W_ff1, ffb1, nullptr, 0, f_ff1, 2048, 4096, 2048, 512);
    gemm_bt<EPI_BIAS_RES, float><<<dim3(32, 4), 256, 0, stream>>>(f_ff1, 2048, wts + W_ff2, ffb2, h2, 512, (float*)d_out, 512, 4096, 512, 2048);
}

// Round 3
// 675.483 us; speedup vs baseline: 2.2560x; 2.2560x over previous
//
#include <hip/hip_runtime.h>
#include <hip/hip_bf16.h>
#include <stdint.h>

using bf16 = __hip_bfloat16;
typedef __attribute__((ext_vector_type(8))) short s16x8;
typedef __attribute__((ext_vector_type(8))) unsigned short u16x8;
typedef __attribute__((ext_vector_type(4))) unsigned short u16x4;
typedef __attribute__((ext_vector_type(4))) float f32x4;

__device__ __forceinline__ float bu2f(unsigned short u) {
    union { unsigned int i; float f; } v; v.i = ((unsigned int)u) << 16; return v.f;
}
__device__ __forceinline__ float b2f(bf16 v) { return __bfloat162float(v); }
__device__ __forceinline__ bf16 f2b(float f) { return __float2bfloat16(f); }
__device__ __forceinline__ unsigned short f2bu(float f) {
    bf16 t = __float2bfloat16(f); return *(unsigned short*)&t;
}
__device__ __forceinline__ void st(bf16* p, float v) { *p = f2b(v); }
__device__ __forceinline__ void st(float* p, float v) { *p = v; }

#define AS1(p) ((__attribute__((address_space(1))) void*)(p))
#define AS3(p) ((__attribute__((address_space(3))) void*)(p))

// ---------------------------------------------------------------- weight cast f32 -> bf16
__global__ __launch_bounds__(256) void cast_weights_k(
    const float* __restrict__ s0, const float* __restrict__ s1,
    const float* __restrict__ s2, const float* __restrict__ s3,
    const float* __restrict__ s4, const float* __restrict__ s5,
    const float* __restrict__ s6, const float* __restrict__ s7,
    const float* __restrict__ s8, const float* __restrict__ s9,
    bf16* __restrict__ dst)
{
    int i = blockIdx.x * 256 + threadIdx.x;
    const float* src; int loc;
    if      (i < 131072) { src = s0; loc = i; }
    else if (i < 262144) { src = s1; loc = i - 131072; }
    else if (i < 270336) { src = s2; loc = i - 262144; }
    else if (i < 278528) { src = s3; loc = i - 270336; }
    else if (i < 282624) { src = s4; loc = i - 278528; }
    else if (i < 286720) { src = s5; loc = i - 282624; }
    else if (i < 352256) { src = s6; loc = i - 286720; }
    else if (i < 417792) { src = s7; loc = i - 352256; }
    else if (i < 548864) { src = s8; loc = i - 417792; }
    else                 { src = s9; loc = i - 548864; }
    f32x4 a = *(const f32x4*)(src + (size_t)loc * 8);
    f32x4 b = *(const f32x4*)(src + (size_t)loc * 8 + 4);
    u16x8 o;
#pragma unroll
    for (int j = 0; j < 4; j++) { o[j] = f2bu(a[j]); o[4 + j] = f2bu(b[j]); }
    *(u16x8*)(dst + (size_t)i * 8) = o;
}

// ---------------------------------------------------------------- layernorm (f32 in, bf16 out)
__global__ __launch_bounds__(256) void layernorm_k(
    const float* __restrict__ x, const float* __restrict__ g, const float* __restrict__ bb,
    bf16* __restrict__ out, int rows_per_b, int out_bstride, int out_roff)
{
    int r = blockIdx.x * 4 + (threadIdx.x >> 6);
    int lane = threadIdx.x & 63;
    const float* xr = x + (size_t)r * 512 + lane * 8;
    f32x4 v0 = *(const f32x4*)(xr);
    f32x4 v1 = *(const f32x4*)(xr + 4);
    float f[8]; float s = 0.f, s2 = 0.f;
#pragma unroll
    for (int j = 0; j < 4; j++) { f[j] = v0[j]; f[4 + j] = v1[j]; }
#pragma unroll
    for (int j = 0; j < 8; j++) { s += f[j]; s2 += f[j] * f[j]; }
#pragma unroll
    for (int o = 1; o < 64; o <<= 1) { s += __shfl_xor(s, o); s2 += __shfl_xor(s2, o); }
    float mu = s * (1.f / 512.f);
    float var = s2 * (1.f / 512.f) - mu * mu;
    float rs = rsqrtf(var + 1e-5f);
    f32x4 g0 = *(const f32x4*)(g + lane * 8);
    f32x4 g1 = *(const f32x4*)(g + lane * 8 + 4);
    f32x4 b0 = *(const f32x4*)(bb + lane * 8);
    f32x4 b1 = *(const f32x4*)(bb + lane * 8 + 4);
    int b = r / rows_per_b, rr = r % rows_per_b;
    bf16* orow = out + ((size_t)b * out_bstride + out_roff + rr) * 512 + lane * 8;
    u16x8 ov;
#pragma unroll
    for (int j = 0; j < 4; j++) {
        ov[j]     = f2bu((f[j]     - mu) * rs * g0[j] + b0[j]);
        ov[4 + j] = f2bu((f[4 + j] - mu) * rs * g1[j] + b1[j]);
    }
    *(u16x8*)orow = ov;
}

// ---------------------------------------------------------------- GEMM  C = epi(A * W^T)
enum { EPI_NONE = 0, EPI_SOFTPLUS = 1, EPI_RES = 2, EPI_RELU = 3, EPI_BIAS_RES = 4 };

template<int EPI, typename OT>
__global__ __launch_bounds__(256, 2) void gemm_bt(
    const bf16* __restrict__ A, int lda,
    const bf16* __restrict__ Wt,
    const float* __restrict__ bias,
    const float* __restrict__ res, int ldres,
    OT* __restrict__ C, int ldc,
    int M, int N, int K)
{
    __shared__ __align__(16) bf16 lA[128 * 32];
    __shared__ __align__(16) bf16 lB[128 * 32];
    const int t = threadIdx.x;
    const int bm = blockIdx.x * 128;
    const int bn = blockIdx.y * 128;
    const int w = t >> 6, l = t & 63;
    const int wm = (w >> 1) * 64, wn = (w & 1) * 64;
    const int lr = l & 15, lk = (l >> 4) * 8;
    f32x4 acc[4][4] = {};

    const int c0 = t, c1 = t + 256;
    const int r0 = c0 >> 2, k0o = (c0 & 3) * 8;
    const int r1 = c1 >> 2, k1o = (c1 & 3) * 8;
    int rb0 = bn + r0; if (rb0 >= N) rb0 = N - 1;
    int rb1 = bn + r1; if (rb1 >= N) rb1 = N - 1;

    for (int kk = 0; kk < K; kk += 32) {
        __builtin_amdgcn_global_load_lds(AS1(A + (size_t)(bm + r0) * lda + kk + k0o), AS3(lA + c0 * 8), 16, 0, 0);
        __builtin_amdgcn_global_load_lds(AS1(A + (size_t)(bm + r1) * lda + kk + k1o), AS3(lA + c1 * 8), 16, 0, 0);
        __builtin_amdgcn_global_load_lds(AS1(Wt + (size_t)rb0 * K + kk + k0o), AS3(lB + c0 * 8), 16, 0, 0);
        __builtin_amdgcn_global_load_lds(AS1(Wt + (size_t)rb1 * K + kk + k1o), AS3(lB + c1 * 8), 16, 0, 0);
        asm volatile("s_waitcnt vmcnt(0)" ::: "memory");
        __syncthreads();
        s16x8 af[4], bfr[4];
#pragma unroll
        for (int m = 0; m < 4; m++) af[m] = *(const s16x8*)(lA + (wm + m * 16 + lr) * 32 + lk);
#pragma unroll
        for (int n = 0; n < 4; n++) bfr[n] = *(const s16x8*)(lB + (wn + n * 16 + lr) * 32 + lk);
#pragma unroll
        for (int m = 0; m < 4; m++)
#pragma unroll
            for (int n = 0; n < 4; n++)
                acc[m][n] = __builtin_amdgcn_mfma_f32_16x16x32_bf16(af[m], bfr[n], acc[m][n], 0, 0, 0);
        __syncthreads();
    }

#pragma unroll
    for (int n = 0; n < 4; n++) {
        int col = bn + wn + n * 16 + lr;
        if (col >= N) continue;
        float bv = 0.f;
        if (EPI == EPI_SOFTPLUS || EPI == EPI_RELU || EPI == EPI_BIAS_RES) bv = bias[col];
#pragma unroll
        for (int m = 0; m < 4; m++) {
#pragma unroll
            for (int i = 0; i < 4; i++) {
                int row = bm + wm + m * 16 + (l >> 4) * 4 + i;
                float v = acc[m][n][i] + bv;
                if (EPI == EPI_SOFTPLUS) v = (v > 20.f) ? v : log1pf(__expf(v));
                if (EPI == EPI_RELU) v = fmaxf(v, 0.f);
                if (EPI == EPI_RES || EPI == EPI_BIAS_RES) v += res[(size_t)row * ldres + col];
                st(&C[(size_t)row * ldc + col], v);
            }
        }
    }
}

// ---------------------------------------------------------------- causal depthwise conv (D_CONV=4) + silu
__global__ __launch_bounds__(128) void conv_silu_k(
    const bf16* __restrict__ xin, const float* __restrict__ cw, const float* __restrict__ cb,
    bf16* __restrict__ xi, int Ltot)
{
    int row = blockIdx.x;
    int tt = row % Ltot;
    int d0 = threadIdx.x * 8;
    float w[4][8];
#pragma unroll
    for (int j = 0; j < 8; j++) {
        f32x4 wv = *(const f32x4*)(cw + (size_t)(d0 + j) * 4);
#pragma unroll
        for (int tap = 0; tap < 4; tap++) w[tap][j] = wv[tap];
    }
    f32x4 cb0 = *(const f32x4*)(cb + d0);
    f32x4 cb1 = *(const f32x4*)(cb + d0 + 4);
    float acc[8];
#pragma unroll
    for (int j = 0; j < 4; j++) { acc[j] = cb0[j]; acc[4 + j] = cb1[j]; }
#pragma unroll
    for (int tap = 0; tap < 4; tap++) {
        int ts = tt - 3 + tap;
        if (ts < 0) continue;
        const u16x8 v = *(const u16x8*)(xin + (size_t)(row - 3 + tap) * 1024 + d0);
#pragma unroll
        for (int j = 0; j < 8; j++) acc[j] = fmaf(w[tap][j], bu2f(v[j]), acc[j]);
    }
    u16x8 ov;
#pragma unroll
    for (int j = 0; j < 8; j++) {
        float a = acc[j];
        ov[j] = f2bu(a / (1.f + __expf(-a)));
    }
    *(u16x8*)(xi + (size_t)row * 1024 + d0) = ov;
}

// ---------------------------------------------------------------- chunked selective scan
// lane = dloc*16 + n (16 d per block: 4 waves x 4 dloc); block = (b, chunk, dblk)
// pass1: per-chunk local scan -> P = prod(dA), E = end state (zero init)
template<int T>
__global__ __launch_bounds__(256) void scan_p1(
    const bf16* __restrict__ delta, const bf16* __restrict__ dbc,
    const bf16* __restrict__ xi, const float* __restrict__ A_log,
    float* __restrict__ P, float* __restrict__ E, int Ltot, int C)
{
    const int t = threadIdx.x;
    const int lane = t & 63, wv = t >> 6;
    const int n = lane & 15, dloc = lane >> 4;
    const int bx = blockIdx.x;
    const int dblk = bx & 63;
    const int c = (bx >> 6) % C;
    const int b = (bx >> 6) / C;
    const int d = dblk * 16 + wv * 4 + dloc;
    const float Af = -__expf(A_log[d * 16 + n]) * 1.442695040888963f;
    const size_t r = (size_t)b * Ltot + (size_t)c * T;
    float h = 0.f, p = 1.f;
#pragma unroll 4
    for (int j = 0; j < T; j++) {
        size_t rn = r + j;
        float dl = b2f(delta[rn * 1024 + d]);
        float xv = b2f(xi[rn * 1024 + d]);
        float Bv = b2f(dbc[rn * 64 + 32 + n]);
        float dA = exp2f(dl * Af);
        p *= dA;
        h = fmaf(dA, h, dl * Bv * xv);
    }
    size_t o = (((size_t)b * C + c) * 1024 + d) * 16 + n;
    P[o] = p; E[o] = h;
}

// pass2: sequential over chunks; H[c] = start state of chunk c
__global__ __launch_bounds__(256) void scan_p2(
    const float* __restrict__ P, const float* __restrict__ E,
    float* __restrict__ H, int C)
{
    int idx = blockIdx.x * 256 + threadIdx.x;      // (b, d, n): 65536
    int b = idx >> 14, dn = idx & 16383;
    size_t base = (size_t)b * C * 16384 + dn;
    float h = 0.f;
    for (int c = 0; c < C; c++) {
        size_t o = base + (size_t)c * 16384;
        H[o] = h;
        h = fmaf(P[o], h, E[o]);
    }
}

// pass3: replay chunk from H[c], emit gated y
template<int T>
__global__ __launch_bounds__(256) void scan_p3(
    const bf16* __restrict__ delta, const bf16* __restrict__ dbc,
    const bf16* __restrict__ xi, const bf16* __restrict__ z,
    const float* __restrict__ A_log, const float* __restrict__ Dp,
    const float* __restrict__ H, bf16* __restrict__ y,
    int Ltot, int C, int c0, int tstart)
{
    const int t = threadIdx.x;
    const int lane = t & 63, wv = t >> 6;
    const int n = lane & 15, dloc = lane >> 4;
    const int bx = blockIdx.x;
    const int dblk = bx & 63;
    const int Cp = C - c0;
    const int c = c0 + (bx >> 6) % Cp;
    const int b = (bx >> 6) / Cp;
    const int d = dblk * 16 + wv * 4 + dloc;
    const float Af = -__expf(A_log[d * 16 + n]) * 1.442695040888963f;
    const float Dv = Dp[d];
    const size_t r = (size_t)b * Ltot + (size_t)c * T;
    float h = H[(((size_t)b * C + c) * 1024 + d) * 16 + n];
#pragma unroll 4
    for (int j = 0; j < T; j++) {
        size_t rn = r + j;
        float dl = b2f(delta[rn * 1024 + d]);
        float xv = b2f(xi[rn * 1024 + d]);
        float Bv = b2f(dbc[rn * 64 + 32 + n]);
        float Cv = b2f(dbc[rn * 64 + 48 + n]);
        float dA = exp2f(dl * Af);
        h = fmaf(dA, h, dl * Bv * xv);
        float s = h * Cv;
        s += __shfl_xor(s, 1); s += __shfl_xor(s, 2);
        s += __shfl_xor(s, 4); s += __shfl_xor(s, 8);
        if (n == 0) {
            float zv = b2f(z[rn * 1024 + d]);
            float yv = (s + xv * Dv) * (zv / (1.f + __expf(-zv)));
            int tg = c * T + j - tstart;
            y[((size_t)b * 1024 + tg) * 1024 + d] = f2b(yv);
        }
    }
}

// ---------------------------------------------------------------- enc_out (f32) -> xcat rows [0,1024) (bf16)
__global__ __launch_bounds__(256) void copy_enc_k(const float* __restrict__ enc, bf16* __restrict__ xcat)
{
    size_t i = (size_t)blockIdx.x * 256 + threadIdx.x;
    size_t b = i >> 16;
    size_t off = (i & 65535) * 8;
    const float* src = enc + b * (1024 * 512) + off;
    f32x4 a = *(const f32x4*)(src);
    f32x4 c = *(const f32x4*)(src + 4);
    u16x8 o;
#pragma unroll
    for (int j = 0; j < 4; j++) { o[j] = f2bu(a[j]); o[4 + j] = f2bu(c[j]); }
    *(u16x8*)(xcat + b * (2048 * 512) + off) = o;
}

// ---------------------------------------------------------------- launch
extern "C" void kernel_launch(void* const* d_in, const int* in_sizes, int n_in,
                              void* d_out, int out_size, void* d_ws, size_t ws_size,
                              hipStream_t stream)
{
    const float* x      = (const float*)d_in[0];
    const float* enc    = (const float*)d_in[1];
    const float* ln1g   = (const float*)d_in[2];
    const float* ln1b   = (const float*)d_in[3];
    const float* ln2g   = (const float*)d_in[4];
    const float* ln2b   = (const float*)d_in[5];
    const float* ln3g   = (const float*)d_in[6];
    const float* ln3b   = (const float*)d_in[7];
    const float* ffw1   = (const float*)d_in[8];
    const float* ffb1   = (const float*)d_in[9];
    const float* ffw2   = (const float*)d_in[10];
    const float* ffb2   = (const float*)d_in[11];
    const float* u_in_w   = (const float*)d_in[12];
    const float* u_conv_w = (const float*)d_in[13];
    const float* u_conv_b = (const float*)d_in[14];
    const float* u_xproj  = (const float*)d_in[15];
    const float* u_dt_w   = (const float*)d_in[16];
    const float* u_dt_b   = (const float*)d_in[17];
    const float* u_A_log  = (const float*)d_in[18];
    const float* u_D      = (const float*)d_in[19];
    const float* u_out_w  = (const float*)d_in[20];
    const float* c_in_w   = (const float*)d_in[21];
    const float* c_conv_w = (const float*)d_in[22];
    const float* c_conv_b = (const float*)d_in[23];
    const float* c_xproj  = (const float*)d_in[24];
    const float* c_dt_w   = (const float*)d_in[25];
    const float* c_dt_b   = (const float*)d_in[26];
    const float* c_A_log  = (const float*)d_in[27];
    const float* c_D      = (const float*)d_in[28];
    const float* c_out_w  = (const float*)d_in[29];

    const size_t MB = 1ull << 20;
    char* W = (char*)d_ws;
    float* h   = (float*)(W + 0 * MB);     // 8MB persistent
    float* h2  = (float*)(W + 8 * MB);     // 8MB persistent
    bf16*  wts = (bf16*)(W + 16 * MB);     // 10.4MB persistent (16..27)
    const size_t W_u_in  = 0;
    const size_t W_c_in  = 1048576;
    const size_t W_u_xp  = 2097152;
    const size_t W_c_xp  = 2162688;
    const size_t W_u_dt  = 2228224;
    const size_t W_c_dt  = 2260992;
    const size_t W_u_out = 2293760;
    const size_t W_c_out = 2818048;
    const size_t W_ff1   = 3342336;
    const size_t W_ff2   = 4390912;
    // self phase arena
    bf16* s_ln1 = (bf16*)(W + 27 * MB);    // 4MB
    bf16* s_x   = (bf16*)(W + 31 * MB);    // 8MB (4,1024,1024)
    bf16* s_z   = (bf16*)(W + 39 * MB);    // 8MB
    bf16* s_xi  = (bf16*)(W + 47 * MB);    // 8MB
    bf16* s_dbc = (bf16*)(W + 55 * MB);    // 0.5MB
    bf16* s_dl  = (bf16*)(W + 31 * MB);    // 8MB over s_x (dead after conv)
    bf16* s_y   = (bf16*)(W + 56 * MB);    // 8MB
    float* sP   = (float*)(W + 64 * MB);   // 4MB (4,16,1024,16) f32
    float* sE   = (float*)(W + 68 * MB);   // 4MB
    float* sH   = (float*)(W + 72 * MB);   // 4MB -> peak 76
    // cross phase arena
    bf16* c_xcat = (bf16*)(W + 27 * MB);   // 8MB (4,2048,512)
    bf16* c_x    = (bf16*)(W + 35 * MB);   // 16MB (4,2048,1024)
    bf16* c_z    = (bf16*)(W + 51 * MB);   // 16MB
    bf16* c_xi   = (bf16*)(W + 67 * MB);   // 16MB
    bf16* c_dbc  = (bf16*)(W + 83 * MB);   // 1MB
    bf16* c_dl   = (bf16*)(W + 35 * MB);   // 16MB over c_x (dead after conv)
    bf16* c_y    = (bf16*)(W + 27 * MB);   // 8MB over c_xcat (dead after in-proj)
    float* cP    = (float*)(W + 84 * MB);  // 4MB
    float* cE    = (float*)(W + 88 * MB);  // 4MB
    float* cH    = (float*)(W + 92 * MB);  // 4MB -> peak 96
    // ff phase arena
    bf16* f_ln3 = (bf16*)(W + 27 * MB);    // 4MB
    bf16* f_ff1 = (bf16*)(W + 31 * MB);    // 16MB

    cast_weights_k<<<2656, 256, 0, stream>>>(u_in_w, c_in_w, u_xproj, c_xproj, u_dt_w,
                                             c_dt_w, u_out_w, c_out_w, ffw1, ffw2, wts);

    // ---------------- self mamba ----------------
    layernorm_k<<<1024, 256, 0, stream>>>(x, ln1g, ln1b, s_ln1, 1024, 1024, 0);
    gemm_bt<EPI_NONE, bf16><<<dim3(32, 8), 256, 0, stream>>>(s_ln1, 512, wts + W_u_in, nullptr, nullptr, 0, s_x, 1024, 4096, 1024, 512);
    gemm_bt<EPI_NONE, bf16><<<dim3(32, 8), 256, 0, stream>>>(s_ln1, 512, wts + W_u_in + 524288, nullptr, nullptr, 0, s_z, 1024, 4096, 1024, 512);
    conv_silu_k<<<4096, 128, 0, stream>>>(s_x, u_conv_w, u_conv_b, s_xi, 1024);
    gemm_bt<EPI_NONE, bf16><<<dim3(32, 1), 256, 0, stream>>>(s_xi, 1024, wts + W_u_xp, nullptr, nullptr, 0, s_dbc, 64, 4096, 64, 1024);
    gemm_bt<EPI_SOFTPLUS, bf16><<<dim3(32, 8), 256, 0, stream>>>(s_dbc, 64, wts + W_u_dt, u_dt_b, nullptr, 0, s_dl, 1024, 4096, 1024, 32);
    scan_p1<64><<<4096, 256, 0, stream>>>(s_dl, s_dbc, s_xi, u_A_log, sP, sE, 1024, 16);
    scan_p2<<<256, 256, 0, stream>>>(sP, sE, sH, 16);
    scan_p3<64><<<4096, 256, 0, stream>>>(s_dl, s_dbc, s_xi, s_z, u_A_log, u_D, sH, s_y, 1024, 16, 0, 0);
    gemm_bt<EPI_RES, float><<<dim3(32, 4), 256, 0, stream>>>(s_y, 1024, wts + W_u_out, nullptr, x, 512, h, 512, 4096, 512, 1024);

    // ---------------- cross mamba ----------------
    copy_enc_k<<<1024, 256, 0, stream>>>(enc, c_xcat);
    layernorm_k<<<1024, 256, 0, stream>>>(h, ln2g, ln2b, c_xcat, 1024, 2048, 1024);
    gemm_bt<EPI_NONE, bf16><<<dim3(64, 8), 256, 0, stream>>>(c_xcat, 512, wts + W_c_in, nullptr, nullptr, 0, c_x, 1024, 8192, 1024, 512);
    gemm_bt<EPI_NONE, bf16><<<dim3(64, 8), 256, 0, stream>>>(c_xcat, 512, wts + W_c_in + 524288, nullptr, nullptr, 0, c_z, 1024, 8192, 1024, 512);
    conv_silu_k<<<8192, 128, 0, stream>>>(c_x, c_conv_w, c_conv_b, c_xi, 2048);
    gemm_bt<EPI_NONE, bf16><<<dim3(64, 1), 256, 0, stream>>>(c_xi, 1024, wts + W_c_xp, nullptr, nullptr, 0, c_dbc, 64, 8192, 64, 1024);
    gemm_bt<EPI_SOFTPLUS, bf16><<<dim3(64, 8), 256, 0, stream>>>(c_dbc, 64, wts + W_c_dt, c_dt_b, nullptr, 0, c_dl, 1024, 8192, 1024, 32);
    scan_p1<128><<<4096, 256, 0, stream>>>(c_dl, c_dbc, c_xi, c_A_log, cP, cE, 2048, 16);
    scan_p2<<<256, 256, 0, stream>>>(cP, cE, cH, 16);
    scan_p3<128><<<2048, 256, 0, stream>>>(c_dl, c_dbc, c_xi, c_z, c_A_log, c_D, cH, c_y, 2048, 16, 8, 1024);
    gemm_bt<EPI_RES, float><<<dim3(32, 4), 256, 0, stream>>>(c_y, 1024, wts + W_c_out, nullptr, h, 512, h2, 512, 4096, 512, 1024);

    // ---------------- feed-forward ----------------
    layernorm_k<<<1024, 256, 0, stream>>>(h2, ln3g, ln3b, f_ln3, 1024, 1024, 0);
    gemm_bt<EPI_RELU, bf16><<<dim3(32, 16), 256, 0, stream>>>(f_ln3, 512, wts + W_ff1, ffb1, nullptr, 0, f_ff1, 2048, 4096, 2048, 512);
    gemm_bt<EPI_BIAS_RES, float><<<dim3(32, 4), 256, 0, stream>>>(f_ff1, 2048, wts + W_ff2, ffb2, h2, 512, (float*)d_out, 512, 4096, 512, 2048);
}

// Round 4
// 463.613 us; speedup vs baseline: 3.2870x; 1.4570x over previous
//
#include <hip/hip_runtime.h>
#include <hip/hip_bf16.h>
#include <stdint.h>

using bf16 = __hip_bfloat16;
typedef __attribute__((ext_vector_type(8))) short s16x8;
typedef __attribute__((ext_vector_type(8))) unsigned short u16x8;
typedef __attribute__((ext_vector_type(4))) unsigned short u16x4;
typedef __attribute__((ext_vector_type(4))) float f32x4;

__device__ __forceinline__ float bu2f(unsigned short u) {
    union { unsigned int i; float f; } v; v.i = ((unsigned int)u) << 16; return v.f;
}
__device__ __forceinline__ float b2f(bf16 v) { return __bfloat162float(v); }
__device__ __forceinline__ bf16 f2b(float f) { return __float2bfloat16(f); }
__device__ __forceinline__ unsigned short f2bu(float f) {
    bf16 t = __float2bfloat16(f); return *(unsigned short*)&t;
}
__device__ __forceinline__ void st(bf16* p, float v) { *p = f2b(v); }
__device__ __forceinline__ void st(float* p, float v) { *p = v; }

#define AS1(p) ((__attribute__((address_space(1))) void*)(p))
#define AS3(p) ((__attribute__((address_space(3))) void*)(p))

// ---------------------------------------------------------------- weight cast f32 -> bf16
__global__ __launch_bounds__(256) void cast_weights_k(
    const float* __restrict__ s0, const float* __restrict__ s1,
    const float* __restrict__ s2, const float* __restrict__ s3,
    const float* __restrict__ s4, const float* __restrict__ s5,
    const float* __restrict__ s6, const float* __restrict__ s7,
    const float* __restrict__ s8, const float* __restrict__ s9,
    bf16* __restrict__ dst)
{
    int i = blockIdx.x * 256 + threadIdx.x;
    const float* src; int loc;
    if      (i < 131072) { src = s0; loc = i; }
    else if (i < 262144) { src = s1; loc = i - 131072; }
    else if (i < 270336) { src = s2; loc = i - 262144; }
    else if (i < 278528) { src = s3; loc = i - 270336; }
    else if (i < 282624) { src = s4; loc = i - 278528; }
    else if (i < 286720) { src = s5; loc = i - 282624; }
    else if (i < 352256) { src = s6; loc = i - 286720; }
    else if (i < 417792) { src = s7; loc = i - 352256; }
    else if (i < 548864) { src = s8; loc = i - 417792; }
    else                 { src = s9; loc = i - 548864; }
    f32x4 a = *(const f32x4*)(src + (size_t)loc * 8);
    f32x4 b = *(const f32x4*)(src + (size_t)loc * 8 + 4);
    u16x8 o;
#pragma unroll
    for (int j = 0; j < 4; j++) { o[j] = f2bu(a[j]); o[4 + j] = f2bu(b[j]); }
    *(u16x8*)(dst + (size_t)i * 8) = o;
}

// ---------------------------------------------------------------- layernorm (f32 in, bf16 out)
__global__ __launch_bounds__(256) void layernorm_k(
    const float* __restrict__ x, const float* __restrict__ g, const float* __restrict__ bb,
    bf16* __restrict__ out, int rows_per_b, int out_bstride, int out_roff)
{
    int r = blockIdx.x * 4 + (threadIdx.x >> 6);
    int lane = threadIdx.x & 63;
    const float* xr = x + (size_t)r * 512 + lane * 8;
    f32x4 v0 = *(const f32x4*)(xr);
    f32x4 v1 = *(const f32x4*)(xr + 4);
    float f[8]; float s = 0.f, s2 = 0.f;
#pragma unroll
    for (int j = 0; j < 4; j++) { f[j] = v0[j]; f[4 + j] = v1[j]; }
#pragma unroll
    for (int j = 0; j < 8; j++) { s += f[j]; s2 += f[j] * f[j]; }
#pragma unroll
    for (int o = 1; o < 64; o <<= 1) { s += __shfl_xor(s, o); s2 += __shfl_xor(s2, o); }
    float mu = s * (1.f / 512.f);
    float var = s2 * (1.f / 512.f) - mu * mu;
    float rs = rsqrtf(var + 1e-5f);
    f32x4 g0 = *(const f32x4*)(g + lane * 8);
    f32x4 g1 = *(const f32x4*)(g + lane * 8 + 4);
    f32x4 b0 = *(const f32x4*)(bb + lane * 8);
    f32x4 b1 = *(const f32x4*)(bb + lane * 8 + 4);
    int b = r / rows_per_b, rr = r % rows_per_b;
    bf16* orow = out + ((size_t)b * out_bstride + out_roff + rr) * 512 + lane * 8;
    u16x8 ov;
#pragma unroll
    for (int j = 0; j < 4; j++) {
        ov[j]     = f2bu((f[j]     - mu) * rs * g0[j] + b0[j]);
        ov[4 + j] = f2bu((f[4 + j] - mu) * rs * g1[j] + b1[j]);
    }
    *(u16x8*)orow = ov;
}

// ---------------------------------------------------------------- GEMM  C = epi(A * W^T)
enum { EPI_NONE = 0, EPI_SOFTPLUS = 1, EPI_RES = 2, EPI_RELU = 3, EPI_BIAS_RES = 4 };

template<int EPI, typename OT>
__global__ __launch_bounds__(256, 2) void gemm_bt(
    const bf16* __restrict__ A, int lda,
    const bf16* __restrict__ Wt,
    const float* __restrict__ bias,
    const float* __restrict__ res, int ldres,
    OT* __restrict__ C, int ldc,
    int M, int N, int K)
{
    __shared__ __align__(16) bf16 lA[128 * 32];
    __shared__ __align__(16) bf16 lB[128 * 32];
    const int t = threadIdx.x;
    const int bm = blockIdx.x * 128;
    const int bn = blockIdx.y * 128;
    const int w = t >> 6, l = t & 63;
    const int wm = (w >> 1) * 64, wn = (w & 1) * 64;
    const int lr = l & 15, lk = (l >> 4) * 8;
    f32x4 acc[4][4] = {};

    const int c0 = t, c1 = t + 256;
    const int r0 = c0 >> 2, k0o = (c0 & 3) * 8;
    const int r1 = c1 >> 2, k1o = (c1 & 3) * 8;
    int rb0 = bn + r0; if (rb0 >= N) rb0 = N - 1;
    int rb1 = bn + r1; if (rb1 >= N) rb1 = N - 1;

    for (int kk = 0; kk < K; kk += 32) {
        __builtin_amdgcn_global_load_lds(AS1(A + (size_t)(bm + r0) * lda + kk + k0o), AS3(lA + c0 * 8), 16, 0, 0);
        __builtin_amdgcn_global_load_lds(AS1(A + (size_t)(bm + r1) * lda + kk + k1o), AS3(lA + c1 * 8), 16, 0, 0);
        __builtin_amdgcn_global_load_lds(AS1(Wt + (size_t)rb0 * K + kk + k0o), AS3(lB + c0 * 8), 16, 0, 0);
        __builtin_amdgcn_global_load_lds(AS1(Wt + (size_t)rb1 * K + kk + k1o), AS3(lB + c1 * 8), 16, 0, 0);
        asm volatile("s_waitcnt vmcnt(0)" ::: "memory");
        __syncthreads();
        s16x8 af[4], bfr[4];
#pragma unroll
        for (int m = 0; m < 4; m++) af[m] = *(const s16x8*)(lA + (wm + m * 16 + lr) * 32 + lk);
#pragma unroll
        for (int n = 0; n < 4; n++) bfr[n] = *(const s16x8*)(lB + (wn + n * 16 + lr) * 32 + lk);
#pragma unroll
        for (int m = 0; m < 4; m++)
#pragma unroll
            for (int n = 0; n < 4; n++)
                acc[m][n] = __builtin_amdgcn_mfma_f32_16x16x32_bf16(af[m], bfr[n], acc[m][n], 0, 0, 0);
        __syncthreads();
    }

#pragma unroll
    for (int n = 0; n < 4; n++) {
        int col = bn + wn + n * 16 + lr;
        if (col >= N) continue;
        float bv = 0.f;
        if (EPI == EPI_SOFTPLUS || EPI == EPI_RELU || EPI == EPI_BIAS_RES) bv = bias[col];
#pragma unroll
        for (int m = 0; m < 4; m++) {
#pragma unroll
            for (int i = 0; i < 4; i++) {
                int row = bm + wm + m * 16 + (l >> 4) * 4 + i;
                float v = acc[m][n][i] + bv;
                if (EPI == EPI_SOFTPLUS) v = (v > 20.f) ? v : log1pf(__expf(v));
                if (EPI == EPI_RELU) v = fmaxf(v, 0.f);
                if (EPI == EPI_RES || EPI == EPI_BIAS_RES) v += res[(size_t)row * ldres + col];
                st(&C[(size_t)row * ldc + col], v);
            }
        }
    }
}

// ---------------------------------------------------------------- causal depthwise conv (D_CONV=4) + silu
__global__ __launch_bounds__(128) void conv_silu_k(
    const bf16* __restrict__ xin, const float* __restrict__ cw, const float* __restrict__ cb,
    bf16* __restrict__ xi, int Ltot)
{
    int row = blockIdx.x;
    int tt = row % Ltot;
    int d0 = threadIdx.x * 8;
    float w[4][8];
#pragma unroll
    for (int j = 0; j < 8; j++) {
        f32x4 wv = *(const f32x4*)(cw + (size_t)(d0 + j) * 4);
#pragma unroll
        for (int tap = 0; tap < 4; tap++) w[tap][j] = wv[tap];
    }
    f32x4 cb0 = *(const f32x4*)(cb + d0);
    f32x4 cb1 = *(const f32x4*)(cb + d0 + 4);
    float acc[8];
#pragma unroll
    for (int j = 0; j < 4; j++) { acc[j] = cb0[j]; acc[4 + j] = cb1[j]; }
#pragma unroll
    for (int tap = 0; tap < 4; tap++) {
        int ts = tt - 3 + tap;
        if (ts < 0) continue;
        const u16x8 v = *(const u16x8*)(xin + (size_t)(row - 3 + tap) * 1024 + d0);
#pragma unroll
        for (int j = 0; j < 8; j++) acc[j] = fmaf(w[tap][j], bu2f(v[j]), acc[j]);
    }
    u16x8 ov;
#pragma unroll
    for (int j = 0; j < 8; j++) {
        float a = acc[j];
        ov[j] = f2bu(a / (1.f + __expf(-a)));
    }
    *(u16x8*)(xi + (size_t)row * 1024 + d0) = ov;
}

// ---------------------------------------------------------------- extract B/C columns of dbc -> f32 rows
// i = (row, n); Bf/Cf layout [row][16] f32 (row = b*Ltot + t)
__global__ __launch_bounds__(256) void extract_bc_k(
    const bf16* __restrict__ dbc, float* __restrict__ Bf, float* __restrict__ Cf)
{
    int i = blockIdx.x * 256 + threadIdx.x;
    int row = i >> 4, n = i & 15;
    Bf[i] = b2f(dbc[(size_t)row * 64 + 32 + n]);
    Cf[i] = b2f(dbc[(size_t)row * 64 + 48 + n]);
}

// ---------------------------------------------------------------- chunked selective scan, d-per-thread
// thread owns channel d; h[0..15] in registers; B/C rows are wave-uniform (s_load).
// pass1: local scan (zero init) -> P[b][c][n][d] = exp2(Af*sum dl), E = end state (bf16)
template<int T>
__global__ __launch_bounds__(256) void scan_p1(
    const bf16* __restrict__ delta, const bf16* __restrict__ xi,
    const float* __restrict__ Bf, const float* __restrict__ A_log,
    bf16* __restrict__ P, bf16* __restrict__ E, int Ltot, int C)
{
    const int tid = threadIdx.x;
    const int bx = blockIdx.x;              // b*(C*4) + c*4 + dg
    const int dg = bx & 3;
    const int c = (bx >> 2) % C;
    const int b = (bx >> 2) / C;
    const int d = dg * 256 + tid;
    const f32x4* Ar = (const f32x4*)(A_log + (size_t)d * 16);
    f32x4 a0 = Ar[0], a1 = Ar[1], a2 = Ar[2], a3 = Ar[3];
    float Af[16];
#pragma unroll
    for (int n = 0; n < 16; n++) {
        float al = (n < 4) ? a0[n] : (n < 8) ? a1[n - 4] : (n < 12) ? a2[n - 8] : a3[n - 12];
        Af[n] = -__expf(al) * 1.442695040888963f;
    }
    const size_t r = (size_t)b * Ltot + (size_t)c * T;
    float h[16];
#pragma unroll
    for (int n = 0; n < 16; n++) h[n] = 0.f;
    float sdl = 0.f;
#pragma unroll 2
    for (int j = 0; j < T; j++) {
        size_t rn = r + j;
        float dl = b2f(delta[rn * 1024 + d]);
        float xv = b2f(xi[rn * 1024 + d]);
        const f32x4* Br = (const f32x4*)(Bf + rn * 16);
        f32x4 B0 = Br[0], B1 = Br[1], B2 = Br[2], B3 = Br[3];
        float dlxv = dl * xv;
        sdl += dl;
#pragma unroll
        for (int n = 0; n < 16; n++) {
            float Bn = (n < 4) ? B0[n] : (n < 8) ? B1[n - 4] : (n < 12) ? B2[n - 8] : B3[n - 12];
            float dA = exp2f(dl * Af[n]);
            h[n] = fmaf(dA, h[n], dlxv * Bn);
        }
    }
    size_t o = (((size_t)b * C + c) * 16) * 1024 + d;
#pragma unroll
    for (int n = 0; n < 16; n++) {
        P[o + (size_t)n * 1024] = f2b(exp2f(Af[n] * sdl));
        E[o + (size_t)n * 1024] = f2b(h[n]);
    }
}

// pass2: sequential over chunks per (b,n,d); writes start state H in-place over P
__global__ __launch_bounds__(256) void scan_p2(
    bf16* __restrict__ P, const bf16* __restrict__ E, int C)
{
    int idx = blockIdx.x * 256 + threadIdx.x;   // 65536 = b*16n*1024d
    int d = idx & 1023;
    int n = (idx >> 10) & 15;
    int b = idx >> 14;
    size_t base = (((size_t)b * C) * 16 + n) * 1024 + d;
    float h = 0.f;
    for (int c = 0; c < C; c += 8) {
        float p[8], e[8];
#pragma unroll
        for (int q = 0; q < 8; q++) {
            size_t o = base + (size_t)(c + q) * 16384;
            p[q] = b2f(P[o]); e[q] = b2f(E[o]);
        }
#pragma unroll
        for (int q = 0; q < 8; q++) {
            size_t o = base + (size_t)(c + q) * 16384;
            P[o] = f2b(h);                 // H = state at chunk start
            h = fmaf(p[q], h, e[q]);
        }
    }
}

// pass3: replay chunk from H, emit gated y (rows >= tstart)
template<int T>
__global__ __launch_bounds__(256) void scan_p3(
    const bf16* __restrict__ delta, const bf16* __restrict__ xi,
    const bf16* __restrict__ z,
    const float* __restrict__ Bf, const float* __restrict__ Cf,
    const float* __restrict__ A_log, const float* __restrict__ Dp,
    const bf16* __restrict__ H, bf16* __restrict__ y,
    int Ltot, int C, int c0, int Cp, int tstart)
{
    const int tid = threadIdx.x;
    const int bx = blockIdx.x;              // b*(Cp*4) + cp*4 + dg
    const int dg = bx & 3;
    const int c = c0 + (bx >> 2) % Cp;
    const int b = (bx >> 2) / Cp;
    const int d = dg * 256 + tid;
    const f32x4* Ar = (const f32x4*)(A_log + (size_t)d * 16);
    f32x4 a0 = Ar[0], a1 = Ar[1], a2 = Ar[2], a3 = Ar[3];
    float Af[16];
#pragma unroll
    for (int n = 0; n < 16; n++) {
        float al = (n < 4) ? a0[n] : (n < 8) ? a1[n - 4] : (n < 12) ? a2[n - 8] : a3[n - 12];
        Af[n] = -__expf(al) * 1.442695040888963f;
    }
    const float Dv = Dp[d];
    const size_t r = (size_t)b * Ltot + (size_t)c * T;
    size_t o = (((size_t)b * C + c) * 16) * 1024 + d;
    float h[16];
#pragma unroll
    for (int n = 0; n < 16; n++) h[n] = b2f(H[o + (size_t)n * 1024]);
#pragma unroll 2
    for (int j = 0; j < T; j++) {
        size_t rn = r + j;
        float dl = b2f(delta[rn * 1024 + d]);
        float xv = b2f(xi[rn * 1024 + d]);
        const f32x4* Br = (const f32x4*)(Bf + rn * 16);
        f32x4 B0 = Br[0], B1 = Br[1], B2 = Br[2], B3 = Br[3];
        const f32x4* Cr = (const f32x4*)(Cf + rn * 16);
        f32x4 C0 = Cr[0], C1 = Cr[1], C2 = Cr[2], C3 = Cr[3];
        float dlxv = dl * xv;
        float s = 0.f;
#pragma unroll
        for (int n = 0; n < 16; n++) {
            float Bn = (n < 4) ? B0[n] : (n < 8) ? B1[n - 4] : (n < 12) ? B2[n - 8] : B3[n - 12];
            float Cn = (n < 4) ? C0[n] : (n < 8) ? C1[n - 4] : (n < 12) ? C2[n - 8] : C3[n - 12];
            float dA = exp2f(dl * Af[n]);
            h[n] = fmaf(dA, h[n], dlxv * Bn);
            s = fmaf(h[n], Cn, s);
        }
        float zv = b2f(z[rn * 1024 + d]);
        float g = zv / (1.f + __expf(-zv));
        int tg = c * T + j - tstart;
        y[((size_t)b * 1024 + tg) * 1024 + d] = f2b((s + xv * Dv) * g);
    }
}

// ---------------------------------------------------------------- enc_out (f32) -> xcat rows [0,1024) (bf16)
__global__ __launch_bounds__(256) void copy_enc_k(const float* __restrict__ enc, bf16* __restrict__ xcat)
{
    size_t i = (size_t)blockIdx.x * 256 + threadIdx.x;
    size_t b = i >> 16;
    size_t off = (i & 65535) * 8;
    const float* src = enc + b * (1024 * 512) + off;
    f32x4 a = *(const f32x4*)(src);
    f32x4 c = *(const f32x4*)(src + 4);
    u16x8 o;
#pragma unroll
    for (int j = 0; j < 4; j++) { o[j] = f2bu(a[j]); o[4 + j] = f2bu(c[j]); }
    *(u16x8*)(xcat + b * (2048 * 512) + off) = o;
}

// ---------------------------------------------------------------- launch
extern "C" void kernel_launch(void* const* d_in, const int* in_sizes, int n_in,
                              void* d_out, int out_size, void* d_ws, size_t ws_size,
                              hipStream_t stream)
{
    const float* x      = (const float*)d_in[0];
    const float* enc    = (const float*)d_in[1];
    const float* ln1g   = (const float*)d_in[2];
    const float* ln1b   = (const float*)d_in[3];
    const float* ln2g   = (const float*)d_in[4];
    const float* ln2b   = (const float*)d_in[5];
    const float* ln3g   = (const float*)d_in[6];
    const float* ln3b   = (const float*)d_in[7];
    const float* ffw1   = (const float*)d_in[8];
    const float* ffb1   = (const float*)d_in[9];
    const float* ffw2   = (const float*)d_in[10];
    const float* ffb2   = (const float*)d_in[11];
    const float* u_in_w   = (const float*)d_in[12];
    const float* u_conv_w = (const float*)d_in[13];
    const float* u_conv_b = (const float*)d_in[14];
    const float* u_xproj  = (const float*)d_in[15];
    const float* u_dt_w   = (const float*)d_in[16];
    const float* u_dt_b   = (const float*)d_in[17];
    const float* u_A_log  = (const float*)d_in[18];
    const float* u_D      = (const float*)d_in[19];
    const float* u_out_w  = (const float*)d_in[20];
    const float* c_in_w   = (const float*)d_in[21];
    const float* c_conv_w = (const float*)d_in[22];
    const float* c_conv_b = (const float*)d_in[23];
    const float* c_xproj  = (const float*)d_in[24];
    const float* c_dt_w   = (const float*)d_in[25];
    const float* c_dt_b   = (const float*)d_in[26];
    const float* c_A_log  = (const float*)d_in[27];
    const float* c_D      = (const float*)d_in[28];
    const float* c_out_w  = (const float*)d_in[29];

    const size_t MB = 1ull << 20;
    const size_t HMB = MB / 2;
    char* W = (char*)d_ws;
    float* h   = (float*)(W + 0 * MB);     // 8MB persistent
    float* h2  = (float*)(W + 8 * MB);     // 8MB persistent
    bf16*  wts = (bf16*)(W + 16 * MB);     // 10.4MB persistent (16..27)
    const size_t W_u_in  = 0;
    const size_t W_c_in  = 1048576;
    const size_t W_u_xp  = 2097152;
    const size_t W_c_xp  = 2162688;
    const size_t W_u_dt  = 2228224;
    const size_t W_c_dt  = 2260992;
    const size_t W_u_out = 2293760;
    const size_t W_c_out = 2818048;
    const size_t W_ff1   = 3342336;
    const size_t W_ff2   = 4390912;
    float* Bf = (float*)(W + 54 * HMB);    // 0.5MB (self) / 0.5MB (cross reuse)
    float* Cf = (float*)(W + 55 * HMB);    // 0.5MB -> ends 28MB
    // self phase arena
    bf16* s_ln1 = (bf16*)(W + 28 * MB);    // 4MB
    bf16* s_x   = (bf16*)(W + 32 * MB);    // 8MB (4,1024,1024)
    bf16* s_z   = (bf16*)(W + 40 * MB);    // 8MB
    bf16* s_xi  = (bf16*)(W + 48 * MB);    // 8MB
    bf16* s_dbc = (bf16*)(W + 56 * MB);    // 0.5MB
    bf16* s_dl  = (bf16*)(W + 32 * MB);    // 8MB overlay s_x (dead after conv)
    bf16* sP    = (bf16*)(W + 113 * HMB);  // 8MB (4,64,16,1024) bf16, 56.5..64.5
    bf16* sE    = (bf16*)(W + 129 * HMB);  // 8MB 64.5..72.5
    bf16* s_y   = (bf16*)(W + 129 * HMB);  // 8MB overlay sE (dead after p2)
    // cross phase arena
    bf16* c_xcat = (bf16*)(W + 28 * MB);   // 8MB (4,2048,512)
    bf16* c_x    = (bf16*)(W + 36 * MB);   // 16MB (4,2048,1024)
    bf16* c_z    = (bf16*)(W + 52 * MB);   // 16MB
    bf16* c_xi   = (bf16*)(W + 68 * MB);   // 16MB -> 84
    bf16* c_dbc  = (bf16*)(W + 84 * MB);   // 1MB  -> 85
    bf16* c_dl   = (bf16*)(W + 36 * MB);   // 16MB overlay c_x (dead after conv)
    bf16* cP     = (bf16*)(W + 28 * MB);   // 8MB overlay c_xcat (dead after in-proj)
    bf16* cE     = (bf16*)(W + 85 * MB);   // 8MB -> 93 (peak)
    bf16* c_y    = (bf16*)(W + 85 * MB);   // 8MB overlay cE (dead after p2)
    // ff phase arena
    bf16* f_ln3 = (bf16*)(W + 28 * MB);    // 4MB
    bf16* f_ff1 = (bf16*)(W + 32 * MB);    // 16MB

    cast_weights_k<<<2656, 256, 0, stream>>>(u_in_w, c_in_w, u_xproj, c_xproj, u_dt_w,
                                             c_dt_w, u_out_w, c_out_w, ffw1, ffw2, wts);

    // ---------------- self mamba (L=1024, T=16, C=64) ----------------
    layernorm_k<<<1024, 256, 0, stream>>>(x, ln1g, ln1b, s_ln1, 1024, 1024, 0);
    gemm_bt<EPI_NONE, bf16><<<dim3(32, 8), 256, 0, stream>>>(s_ln1, 512, wts + W_u_in, nullptr, nullptr, 0, s_x, 1024, 4096, 1024, 512);
    gemm_bt<EPI_NONE, bf16><<<dim3(32, 8), 256, 0, stream>>>(s_ln1, 512, wts + W_u_in + 524288, nullptr, nullptr, 0, s_z, 1024, 4096, 1024, 512);
    conv_silu_k<<<4096, 128, 0, stream>>>(s_x, u_conv_w, u_conv_b, s_xi, 1024);
    gemm_bt<EPI_NONE, bf16><<<dim3(32, 1), 256, 0, stream>>>(s_xi, 1024, wts + W_u_xp, nullptr, nullptr, 0, s_dbc, 64, 4096, 64, 1024);
    gemm_bt<EPI_SOFTPLUS, bf16><<<dim3(32, 8), 256, 0, stream>>>(s_dbc, 64, wts + W_u_dt, u_dt_b, nullptr, 0, s_dl, 1024, 4096, 1024, 32);
    extract_bc_k<<<256, 256, 0, stream>>>(s_dbc, Bf, Cf);
    scan_p1<16><<<1024, 256, 0, stream>>>(s_dl, s_xi, Bf, u_A_log, sP, sE, 1024, 64);
    scan_p2<<<256, 256, 0, stream>>>(sP, sE, 64);
    scan_p3<16><<<1024, 256, 0, stream>>>(s_dl, s_xi, s_z, Bf, Cf, u_A_log, u_D, sP, s_y, 1024, 64, 0, 64, 0);
    gemm_bt<EPI_RES, float><<<dim3(32, 4), 256, 0, stream>>>(s_y, 1024, wts + W_u_out, nullptr, x, 512, h, 512, 4096, 512, 1024);

    // ---------------- cross mamba (L=2048, T=32, C=64) ----------------
    copy_enc_k<<<1024, 256, 0, stream>>>(enc, c_xcat);
    layernorm_k<<<1024, 256, 0, stream>>>(h, ln2g, ln2b, c_xcat, 1024, 2048, 1024);
    gemm_bt<EPI_NONE, bf16><<<dim3(64, 8), 256, 0, stream>>>(c_xcat, 512, wts + W_c_in, nullptr, nullptr, 0, c_x, 1024, 8192, 1024, 512);
    gemm_bt<EPI_NONE, bf16><<<dim3(64, 8), 256, 0, stream>>>(c_xcat, 512, wts + W_c_in + 524288, nullptr, nullptr, 0, c_z, 1024, 8192, 1024, 512);
    conv_silu_k<<<8192, 128, 0, stream>>>(c_x, c_conv_w, c_conv_b, c_xi, 2048);
    gemm_bt<EPI_NONE, bf16><<<dim3(64, 1), 256, 0, stream>>>(c_xi, 1024, wts + W_c_xp, nullptr, nullptr, 0, c_dbc, 64, 8192, 64, 1024);
    gemm_bt<EPI_SOFTPLUS, bf16><<<dim3(64, 8), 256, 0, stream>>>(c_dbc, 64, wts + W_c_dt, c_dt_b, nullptr, 0, c_dl, 1024, 8192, 1024, 32);
    extract_bc_k<<<512, 256, 0, stream>>>(c_dbc, Bf, Cf);
    scan_p1<32><<<1024, 256, 0, stream>>>(c_dl, c_xi, Bf, c_A_log, cP, cE, 2048, 64);
    scan_p2<<<256, 256, 0, stream>>>(cP, cE, 64);
    scan_p3<32><<<512, 256, 0, stream>>>(c_dl, c_xi, c_z, Bf, Cf, c_A_log, c_D, cP, c_y, 2048, 64, 32, 32, 1024);
    gemm_bt<EPI_RES, float><<<dim3(32, 4), 256, 0, stream>>>(c_y, 1024, wts + W_c_out, nullptr, h, 512, h2, 512, 4096, 512, 1024);

    // ---------------- feed-forward ----------------
    layernorm_k<<<1024, 256, 0, stream>>>(h2, ln3g, ln3b, f_ln3, 1024, 1024, 0);
    gemm_bt<EPI_RELU, bf16><<<dim3(32, 16), 256, 0, stream>>>(f_ln3, 512, wts + W_ff1, ffb1, nullptr, 0, f_ff1, 2048, 4096, 2048, 512);
    gemm_bt<EPI_BIAS_RES, float><<<dim3(32, 4), 256, 0, stream>>>(f_ff1, 2048, wts + W_ff2, ffb2, h2, 512, (float*)d_out, 512, 4096, 512, 2048);
}